// Round 8
// baseline (1313.721 us; speedup 1.0000x reference)
//
#include <hip/hip_runtime.h>

#define TT   256
#define INH  28
#define HH   64
#define OUTN 10

// tanh(x) = 1 - 2/(e^{2x}+1), clamped so e^{2x} can't overflow.
__device__ __forceinline__ float fast_tanh(float x) {
    float cx = fminf(fmaxf(x, -15.0f), 15.0f);
    float e2 = __expf(2.0f * cx);
    return 1.0f - 2.0f * __builtin_amdgcn_rcpf(e2 + 1.0f);
}

// ============================ v1: rnn2_fused ================================
// ONE wave per block, 2 batch rows, ALL weights per lane (220 floats).
// waves_per_eu(2,2) pins occupancy so the allocator can use up to 256 VGPRs.
// x prefetched one step ahead via LDS staging; h state round-trips LDS
// wave-synchronously (no barriers).
__global__ __launch_bounds__(64)
__attribute__((amdgpu_waves_per_eu(2, 2)))
void rnn2_fused(const float* __restrict__ x,
                const float* __restrict__ Wih0, const float* __restrict__ Whh0,
                const float* __restrict__ bih0, const float* __restrict__ bhh0,
                const float* __restrict__ Wih1, const float* __restrict__ Whh1,
                const float* __restrict__ bih1, const float* __restrict__ bhh1,
                const float* __restrict__ Wfc,  const float* __restrict__ bfc,
                float* __restrict__ out, int row0)
{
    __shared__ __align__(16) float h0s[2][HH];
    __shared__ __align__(16) float h1s[2][HH];
    __shared__ __align__(16) float xl[2][64];

    const int lane = threadIdx.x;
    const int b0 = row0 + (int)blockIdx.x * 2;
    const int b1 = b0 + 1;

    float wih0[INH];
#pragma unroll
    for (int k = 0; k < INH; ++k) wih0[k] = Wih0[lane * INH + k];
    float whh0[HH];
#pragma unroll
    for (int k = 0; k < HH; ++k) whh0[k] = Whh0[lane * HH + k];
    float wih1[HH];
#pragma unroll
    for (int k = 0; k < HH; ++k) wih1[k] = Wih1[lane * HH + k];
    float whh1[HH];
#pragma unroll
    for (int k = 0; k < HH; ++k) whh1[k] = Whh1[lane * HH + k];

    const float bias0 = bih0[lane] + bhh0[lane];
    const float bias1 = bih1[lane] + bhh1[lane];

    int xrow = (lane < INH) ? b0 : b1;
    int xcol = (lane < INH) ? lane : (lane - INH);
    if (lane >= 2 * INH) { xrow = b1; xcol = INH - 1; }
    const float* xbase = x + (size_t)xrow * (TT * INH) + xcol;

    h0s[0][lane] = 0.0f; h0s[1][lane] = 0.0f;
    h1s[0][lane] = 0.0f; h1s[1][lane] = 0.0f;
    xl[0][lane] = xbase[0];

    const float4* h0q0 = (const float4*)h0s[0];
    const float4* h0q1 = (const float4*)h0s[1];
    const float4* h1q0 = (const float4*)h1s[0];
    const float4* h1q1 = (const float4*)h1s[1];

#pragma unroll 1
    for (int t = 0; t < TT; ++t) {
        const int tn = (t + 1 < TT) ? (t + 1) : (TT - 1);
        const float xv = xbase[(size_t)tn * INH];
        const float4* xq = (const float4*)xl[t & 1];

        float pa0 = bias0, pb0 = 0.0f, pa1 = bias0, pb1 = 0.0f;
#pragma unroll
        for (int i = 0; i < 7; ++i) {
            float4 a = xq[i], b = xq[7 + i];
            pa0 = fmaf(a.x, wih0[4*i+0], pa0); pa1 = fmaf(b.x, wih0[4*i+0], pa1);
            pb0 = fmaf(a.y, wih0[4*i+1], pb0); pb1 = fmaf(b.y, wih0[4*i+1], pb1);
            pa0 = fmaf(a.z, wih0[4*i+2], pa0); pa1 = fmaf(b.z, wih0[4*i+2], pa1);
            pb0 = fmaf(a.w, wih0[4*i+3], pb0); pb1 = fmaf(b.w, wih0[4*i+3], pb1);
        }
#pragma unroll
        for (int kk = 0; kk < 16; ++kk) {
            float4 a = h0q0[kk], b = h0q1[kk];
            pa0 = fmaf(a.x, whh0[4*kk+0], pa0); pa1 = fmaf(b.x, whh0[4*kk+0], pa1);
            pb0 = fmaf(a.y, whh0[4*kk+1], pb0); pb1 = fmaf(b.y, whh0[4*kk+1], pb1);
            pa0 = fmaf(a.z, whh0[4*kk+2], pa0); pa1 = fmaf(b.z, whh0[4*kk+2], pa1);
            pb0 = fmaf(a.w, whh0[4*kk+3], pb0); pb1 = fmaf(b.w, whh0[4*kk+3], pb1);
        }
        const float nh00 = fast_tanh(pa0 + pb0);
        const float nh01 = fast_tanh(pa1 + pb1);
        h0s[0][lane] = nh00;
        h0s[1][lane] = nh01;

        float qa0 = bias1, qb0 = 0.0f, qa1 = bias1, qb1 = 0.0f;
#pragma unroll
        for (int kk = 0; kk < 16; ++kk) {
            float4 c = h1q0[kk], d = h1q1[kk];
            qa0 = fmaf(c.x, whh1[4*kk+0], qa0); qa1 = fmaf(d.x, whh1[4*kk+0], qa1);
            qb0 = fmaf(c.y, whh1[4*kk+1], qb0); qb1 = fmaf(d.y, whh1[4*kk+1], qb1);
            qa0 = fmaf(c.z, whh1[4*kk+2], qa0); qa1 = fmaf(d.z, whh1[4*kk+2], qa1);
            qb0 = fmaf(c.w, whh1[4*kk+3], qb0); qb1 = fmaf(d.w, whh1[4*kk+3], qb1);
        }
#pragma unroll
        for (int kk = 0; kk < 16; ++kk) {
            float4 a = h0q0[kk], b = h0q1[kk];
            qa0 = fmaf(a.x, wih1[4*kk+0], qa0); qa1 = fmaf(b.x, wih1[4*kk+0], qa1);
            qb0 = fmaf(a.y, wih1[4*kk+1], qb0); qb1 = fmaf(b.y, wih1[4*kk+1], qb1);
            qa0 = fmaf(a.z, wih1[4*kk+2], qa0); qa1 = fmaf(b.z, wih1[4*kk+2], qa1);
            qb0 = fmaf(a.w, wih1[4*kk+3], qb0); qb1 = fmaf(b.w, wih1[4*kk+3], qb1);
        }
        h1s[0][lane] = fast_tanh(qa0 + qb0);
        h1s[1][lane] = fast_tanh(qa1 + qb1);

        xl[(t + 1) & 1][lane] = xv;
    }

    if (lane < OUTN) {
        const float4* wrow = (const float4*)(Wfc + lane * HH);
        float acc0 = bfc[lane];
        float acc1 = acc0;
#pragma unroll
        for (int kk = 0; kk < 16; ++kk) {
            float4 w = wrow[kk];
            float4 a = h1q0[kk], b = h1q1[kk];
            acc0 = fmaf(a.x, w.x, acc0); acc1 = fmaf(b.x, w.x, acc1);
            acc0 = fmaf(a.y, w.y, acc0); acc1 = fmaf(b.y, w.y, acc1);
            acc0 = fmaf(a.z, w.z, acc0); acc1 = fmaf(b.z, w.z, acc1);
            acc0 = fmaf(a.w, w.w, acc0); acc1 = fmaf(b.w, w.w, acc1);
        }
        out[(size_t)b0 * OUTN + lane] = acc0;
        out[(size_t)b1 * OUTN + lane] = acc1;
    }
}

// ============================ v2: rnn2_split ================================
// TWO-wave block, layer-split software pipeline: wave0 computes layer-0 step
// t, wave1 computes layer-1 step t-2 (depth-2 LDS ring for h0 handoff, one
// __syncthreads per iteration). Weight arrays manually OVERLAID (wA/wB) so
// per-lane weights = 128 floats for both waves — honest VGPR fit without
// AGPR shuttles regardless of allocator heuristics.
// Ring schedule: wave0 publishes h0(t-1)->slot[(t-1)&1] then reads it
// (in-order DS); wave1 reads slot[t&1]=h0(t-2) — opposite parity, so no
// same-iteration conflict; all cross-wave deps separated by the barrier.
__global__ __launch_bounds__(128)
__attribute__((amdgpu_waves_per_eu(2, 2)))
void rnn2_split(const float* __restrict__ x,
                const float* __restrict__ Wih0, const float* __restrict__ Whh0,
                const float* __restrict__ bih0, const float* __restrict__ bhh0,
                const float* __restrict__ Wih1, const float* __restrict__ Whh1,
                const float* __restrict__ bih1, const float* __restrict__ bhh1,
                const float* __restrict__ Wfc,  const float* __restrict__ bfc,
                float* __restrict__ out, int row0)
{
    __shared__ __align__(16) float ring[2][2][HH];  // [slot][row][unit]
    __shared__ __align__(16) float h1s[2][HH];      // wave1-private state
    __shared__ __align__(16) float xl[2][64];       // wave0-private staging

    const int tid  = threadIdx.x;
    const int lane = tid & 63;
    const int wave = tid >> 6;                      // 0 or 1
    const int b0 = row0 + (int)blockIdx.x * 2;
    const int b1 = b0 + 1;

    float wA[HH], wB[HH];                           // overlaid weight rows
    float bias;
    if (wave == 0) {
#pragma unroll
        for (int k = 0; k < HH; ++k) wA[k] = Whh0[lane * HH + k];
#pragma unroll
        for (int k = 0; k < INH; ++k) wB[k] = Wih0[lane * INH + k];
#pragma unroll
        for (int k = INH; k < HH; ++k) wB[k] = 0.0f;
        bias = bih0[lane] + bhh0[lane];
    } else {
#pragma unroll
        for (int k = 0; k < HH; ++k) wA[k] = Whh1[lane * HH + k];
#pragma unroll
        for (int k = 0; k < HH; ++k) wB[k] = Wih1[lane * HH + k];
        bias = bih1[lane] + bhh1[lane];
    }

    int xrow = (lane < INH) ? b0 : b1;
    int xcol = (lane < INH) ? lane : (lane - INH);
    if (lane >= 2 * INH) { xrow = b1; xcol = INH - 1; }
    const float* xbase = x + (size_t)xrow * (TT * INH) + xcol;

    if (wave == 0) {
        ring[0][0][lane] = 0.0f; ring[0][1][lane] = 0.0f;
        ring[1][0][lane] = 0.0f; ring[1][1][lane] = 0.0f;
        xl[0][lane] = xbase[0];
    } else {
        h1s[0][lane] = 0.0f; h1s[1][lane] = 0.0f;
    }
    __syncthreads();

    float nh00 = 0.0f, nh01 = 0.0f;                 // wave0's carried h0(t-1)

    const float4* h1q0 = (const float4*)h1s[0];
    const float4* h1q1 = (const float4*)h1s[1];

#pragma unroll 1
    for (int t = 0; t <= TT + 1; ++t) {
        if (wave == 0) {
            if (t >= 1 && t <= TT) {                // publish h0(t-1)
                ring[(t - 1) & 1][0][lane] = nh00;
                ring[(t - 1) & 1][1][lane] = nh01;
            }
            if (t < TT) {                           // compute h0(t)
                const int tn = (t + 1 < TT) ? (t + 1) : (TT - 1);
                const float xv = xbase[(size_t)tn * INH];
                const float4* xq = (const float4*)xl[t & 1];
                const float4* s0 = (const float4*)ring[(t + 1) & 1][0]; // = (t-1)&1
                const float4* s1 = (const float4*)ring[(t + 1) & 1][1];
                float pa0 = bias, pb0 = 0.0f, pa1 = bias, pb1 = 0.0f;
#pragma unroll
                for (int i = 0; i < 7; ++i) {
                    float4 a = xq[i], b = xq[7 + i];
                    pa0 = fmaf(a.x, wB[4*i+0], pa0); pa1 = fmaf(b.x, wB[4*i+0], pa1);
                    pb0 = fmaf(a.y, wB[4*i+1], pb0); pb1 = fmaf(b.y, wB[4*i+1], pb1);
                    pa0 = fmaf(a.z, wB[4*i+2], pa0); pa1 = fmaf(b.z, wB[4*i+2], pa1);
                    pb0 = fmaf(a.w, wB[4*i+3], pb0); pb1 = fmaf(b.w, wB[4*i+3], pb1);
                }
#pragma unroll
                for (int kk = 0; kk < 16; ++kk) {
                    float4 a = s0[kk], b = s1[kk];
                    pa0 = fmaf(a.x, wA[4*kk+0], pa0); pa1 = fmaf(b.x, wA[4*kk+0], pa1);
                    pb0 = fmaf(a.y, wA[4*kk+1], pb0); pb1 = fmaf(b.y, wA[4*kk+1], pb1);
                    pa0 = fmaf(a.z, wA[4*kk+2], pa0); pa1 = fmaf(b.z, wA[4*kk+2], pa1);
                    pb0 = fmaf(a.w, wA[4*kk+3], pb0); pb1 = fmaf(b.w, wA[4*kk+3], pb1);
                }
                nh00 = fast_tanh(pa0 + pb0);
                nh01 = fast_tanh(pa1 + pb1);
                xl[(t + 1) & 1][lane] = xv;
            }
        } else {
            if (t >= 2) {                           // compute h1(t-2)
                const float4* s0 = (const float4*)ring[t & 1][0];   // (t-2)&1
                const float4* s1 = (const float4*)ring[t & 1][1];
                float qa0 = bias, qb0 = 0.0f, qa1 = bias, qb1 = 0.0f;
#pragma unroll
                for (int kk = 0; kk < 16; ++kk) {
                    float4 a = s0[kk], b = s1[kk];
                    qa0 = fmaf(a.x, wB[4*kk+0], qa0); qa1 = fmaf(b.x, wB[4*kk+0], qa1);
                    qb0 = fmaf(a.y, wB[4*kk+1], qb0); qb1 = fmaf(b.y, wB[4*kk+1], qb1);
                    qa0 = fmaf(a.z, wB[4*kk+2], qa0); qa1 = fmaf(b.z, wB[4*kk+2], qa1);
                    qb0 = fmaf(a.w, wB[4*kk+3], qb0); qb1 = fmaf(b.w, wB[4*kk+3], qb1);
                }
#pragma unroll
                for (int kk = 0; kk < 16; ++kk) {
                    float4 c = h1q0[kk], d = h1q1[kk];
                    qa0 = fmaf(c.x, wA[4*kk+0], qa0); qa1 = fmaf(d.x, wA[4*kk+0], qa1);
                    qb0 = fmaf(c.y, wA[4*kk+1], qb0); qb1 = fmaf(d.y, wA[4*kk+1], qb1);
                    qa0 = fmaf(c.z, wA[4*kk+2], qa0); qa1 = fmaf(d.z, wA[4*kk+2], qa1);
                    qb0 = fmaf(c.w, wA[4*kk+3], qb0); qb1 = fmaf(d.w, wA[4*kk+3], qb1);
                }
                h1s[0][lane] = fast_tanh(qa0 + qb0);
                h1s[1][lane] = fast_tanh(qa1 + qb1);
            }
        }
        __syncthreads();
    }

    if (wave == 1 && lane < OUTN) {
        const float4* wrow = (const float4*)(Wfc + lane * HH);
        float acc0 = bfc[lane];
        float acc1 = acc0;
#pragma unroll
        for (int kk = 0; kk < 16; ++kk) {
            float4 w = wrow[kk];
            float4 a = h1q0[kk], b = h1q1[kk];
            acc0 = fmaf(a.x, w.x, acc0); acc1 = fmaf(b.x, w.x, acc1);
            acc0 = fmaf(a.y, w.y, acc0); acc1 = fmaf(b.y, w.y, acc1);
            acc0 = fmaf(a.z, w.z, acc0); acc1 = fmaf(b.z, w.z, acc1);
            acc0 = fmaf(a.w, w.w, acc0); acc1 = fmaf(b.w, w.w, acc1);
        }
        out[(size_t)b0 * OUTN + lane] = acc0;
        out[(size_t)b1 * OUTN + lane] = acc1;
    }
}

extern "C" void kernel_launch(void* const* d_in, const int* in_sizes, int n_in,
                              void* d_out, int out_size, void* d_ws, size_t ws_size,
                              hipStream_t stream) {
    const float* x    = (const float*)d_in[0];
    const float* Wih0 = (const float*)d_in[1];
    const float* Whh0 = (const float*)d_in[2];
    const float* bih0 = (const float*)d_in[3];
    const float* bhh0 = (const float*)d_in[4];
    const float* Wih1 = (const float*)d_in[5];
    const float* Whh1 = (const float*)d_in[6];
    const float* bih1 = (const float*)d_in[7];
    const float* bhh1 = (const float*)d_in[8];
    const float* Wfc  = (const float*)d_in[9];
    const float* bfc  = (const float*)d_in[10];
    float* out = (float*)d_out;

    // Within-probe A/B: v1 takes rows 0..2047, v2 takes rows 2048..4095.
    rnn2_fused<<<1024, 64, 0, stream>>>(x, Wih0, Whh0, bih0, bhh0,
                                        Wih1, Whh1, bih1, bhh1, Wfc, bfc, out, 0);
    rnn2_split<<<1024, 128, 0, stream>>>(x, Wih0, Whh0, bih0, bhh0,
                                         Wih1, Whh1, bih1, bhh1, Wfc, bfc, out, 2048);
}

// Round 9
// 692.082 us; speedup vs baseline: 1.8982x; 1.8982x over previous
//
#include <hip/hip_runtime.h>

#define TT   256
#define INH  28
#define HH   64
#define OUTN 10

// tanh(x) = 1 - 2/(e^{2x}+1), clamped so e^{2x} can't overflow.
__device__ __forceinline__ float fast_tanh(float x) {
    float cx = fminf(fmaxf(x, -15.0f), 15.0f);
    float e2 = __expf(2.0f * cx);
    return 1.0f - 2.0f * __builtin_amdgcn_rcpf(e2 + 1.0f);
}

// R8 A/B winner, full batch. TWO-wave block, layer-split software pipeline:
// wave0 computes layer-0 step t, wave1 computes layer-1 step t-2 (depth-2
// LDS ring for h0 handoff, one __syncthreads per iteration). Weight arrays
// manually OVERLAID (wA/wB) so per-lane weights = 128 floats for both waves
// — honest VGPR fit (R8: the 220-float fused variant was forced to 124 VGPR
// + AGPR shuttles and ran 2.5x slower; this structure measured 378 µs/half).
// __launch_bounds__(128,3): VGPR cap ~170 (no spill risk at ~150-165 live),
// 3 waves/SIMD; if allocator lands <=128, 4/SIMD and the grid fits 1 pass.
// Ring schedule: wave0 publishes h0(t-1)->slot[(t-1)&1] then reads it
// (in-order DS); wave1 reads slot[t&1]=h0(t-2) — opposite parity, so no
// same-iteration conflict; all cross-wave deps separated by the barrier.
__global__ __launch_bounds__(128, 3)
void rnn2_split(const float* __restrict__ x,
                const float* __restrict__ Wih0, const float* __restrict__ Whh0,
                const float* __restrict__ bih0, const float* __restrict__ bhh0,
                const float* __restrict__ Wih1, const float* __restrict__ Whh1,
                const float* __restrict__ bih1, const float* __restrict__ bhh1,
                const float* __restrict__ Wfc,  const float* __restrict__ bfc,
                float* __restrict__ out)
{
    __shared__ __align__(16) float ring[2][2][HH];  // [slot][row][unit]
    __shared__ __align__(16) float h1s[2][HH];      // wave1-private state
    __shared__ __align__(16) float xl[2][64];       // wave0-private staging

    const int tid  = threadIdx.x;
    const int lane = tid & 63;
    const int wave = tid >> 6;                      // 0 or 1
    const int b0 = (int)blockIdx.x * 2;
    const int b1 = b0 + 1;

    float wA[HH], wB[HH];                           // overlaid weight rows
    float bias;
    if (wave == 0) {
#pragma unroll
        for (int k = 0; k < HH; ++k) wA[k] = Whh0[lane * HH + k];
#pragma unroll
        for (int k = 0; k < INH; ++k) wB[k] = Wih0[lane * INH + k];
#pragma unroll
        for (int k = INH; k < HH; ++k) wB[k] = 0.0f;
        bias = bih0[lane] + bhh0[lane];
    } else {
#pragma unroll
        for (int k = 0; k < HH; ++k) wA[k] = Whh1[lane * HH + k];
#pragma unroll
        for (int k = 0; k < HH; ++k) wB[k] = Wih1[lane * HH + k];
        bias = bih1[lane] + bhh1[lane];
    }

    int xrow = (lane < INH) ? b0 : b1;
    int xcol = (lane < INH) ? lane : (lane - INH);
    if (lane >= 2 * INH) { xrow = b1; xcol = INH - 1; }
    const float* xbase = x + (size_t)xrow * (TT * INH) + xcol;

    if (wave == 0) {
        ring[0][0][lane] = 0.0f; ring[0][1][lane] = 0.0f;
        ring[1][0][lane] = 0.0f; ring[1][1][lane] = 0.0f;
        xl[0][lane] = xbase[0];
    } else {
        h1s[0][lane] = 0.0f; h1s[1][lane] = 0.0f;
    }
    __syncthreads();

    float nh00 = 0.0f, nh01 = 0.0f;                 // wave0's carried h0(t-1)

    const float4* h1q0 = (const float4*)h1s[0];
    const float4* h1q1 = (const float4*)h1s[1];

#pragma unroll 1
    for (int t = 0; t <= TT + 1; ++t) {
        if (wave == 0) {
            if (t >= 1 && t <= TT) {                // publish h0(t-1)
                ring[(t - 1) & 1][0][lane] = nh00;
                ring[(t - 1) & 1][1][lane] = nh01;
            }
            if (t < TT) {                           // compute h0(t)
                const int tn = (t + 1 < TT) ? (t + 1) : (TT - 1);
                const float xv = xbase[(size_t)tn * INH];
                const float4* xq = (const float4*)xl[t & 1];
                const float4* s0 = (const float4*)ring[(t + 1) & 1][0]; // = (t-1)&1
                const float4* s1 = (const float4*)ring[(t + 1) & 1][1];
                float pa0 = bias, pb0 = 0.0f, pa1 = bias, pb1 = 0.0f;
#pragma unroll
                for (int i = 0; i < 7; ++i) {
                    float4 a = xq[i], b = xq[7 + i];
                    pa0 = fmaf(a.x, wB[4*i+0], pa0); pa1 = fmaf(b.x, wB[4*i+0], pa1);
                    pb0 = fmaf(a.y, wB[4*i+1], pb0); pb1 = fmaf(b.y, wB[4*i+1], pb1);
                    pa0 = fmaf(a.z, wB[4*i+2], pa0); pa1 = fmaf(b.z, wB[4*i+2], pa1);
                    pb0 = fmaf(a.w, wB[4*i+3], pb0); pb1 = fmaf(b.w, wB[4*i+3], pb1);
                }
#pragma unroll
                for (int kk = 0; kk < 16; ++kk) {
                    float4 a = s0[kk], b = s1[kk];
                    pa0 = fmaf(a.x, wA[4*kk+0], pa0); pa1 = fmaf(b.x, wA[4*kk+0], pa1);
                    pb0 = fmaf(a.y, wA[4*kk+1], pb0); pb1 = fmaf(b.y, wA[4*kk+1], pb1);
                    pa0 = fmaf(a.z, wA[4*kk+2], pa0); pa1 = fmaf(b.z, wA[4*kk+2], pa1);
                    pb0 = fmaf(a.w, wA[4*kk+3], pb0); pb1 = fmaf(b.w, wA[4*kk+3], pb1);
                }
                nh00 = fast_tanh(pa0 + pb0);
                nh01 = fast_tanh(pa1 + pb1);
                xl[(t + 1) & 1][lane] = xv;
            }
        } else {
            if (t >= 2) {                           // compute h1(t-2)
                const float4* s0 = (const float4*)ring[t & 1][0];   // (t-2)&1
                const float4* s1 = (const float4*)ring[t & 1][1];
                float qa0 = bias, qb0 = 0.0f, qa1 = bias, qb1 = 0.0f;
#pragma unroll
                for (int kk = 0; kk < 16; ++kk) {
                    float4 a = s0[kk], b = s1[kk];
                    qa0 = fmaf(a.x, wB[4*kk+0], qa0); qa1 = fmaf(b.x, wB[4*kk+0], qa1);
                    qb0 = fmaf(a.y, wB[4*kk+1], qb0); qb1 = fmaf(b.y, wB[4*kk+1], qb1);
                    qa0 = fmaf(a.z, wB[4*kk+2], qa0); qa1 = fmaf(b.z, wB[4*kk+2], qa1);
                    qb0 = fmaf(a.w, wB[4*kk+3], qb0); qb1 = fmaf(b.w, wB[4*kk+3], qb1);
                }
#pragma unroll
                for (int kk = 0; kk < 16; ++kk) {
                    float4 c = h1q0[kk], d = h1q1[kk];
                    qa0 = fmaf(c.x, wA[4*kk+0], qa0); qa1 = fmaf(d.x, wA[4*kk+0], qa1);
                    qb0 = fmaf(c.y, wA[4*kk+1], qb0); qb1 = fmaf(d.y, wA[4*kk+1], qb1);
                    qa0 = fmaf(c.z, wA[4*kk+2], qa0); qa1 = fmaf(d.z, wA[4*kk+2], qa1);
                    qb0 = fmaf(c.w, wA[4*kk+3], qb0); qb1 = fmaf(d.w, wA[4*kk+3], qb1);
                }
                h1s[0][lane] = fast_tanh(qa0 + qb0);
                h1s[1][lane] = fast_tanh(qa1 + qb1);
            }
        }
        __syncthreads();
    }

    if (wave == 1 && lane < OUTN) {
        const float4* wrow = (const float4*)(Wfc + lane * HH);
        float acc0 = bfc[lane];
        float acc1 = acc0;
#pragma unroll
        for (int kk = 0; kk < 16; ++kk) {
            float4 w = wrow[kk];
            float4 a = h1q0[kk], b = h1q1[kk];
            acc0 = fmaf(a.x, w.x, acc0); acc1 = fmaf(b.x, w.x, acc1);
            acc0 = fmaf(a.y, w.y, acc0); acc1 = fmaf(b.y, w.y, acc1);
            acc0 = fmaf(a.z, w.z, acc0); acc1 = fmaf(b.z, w.z, acc1);
            acc0 = fmaf(a.w, w.w, acc0); acc1 = fmaf(b.w, w.w, acc1);
        }
        out[(size_t)b0 * OUTN + lane] = acc0;
        out[(size_t)b1 * OUTN + lane] = acc1;
    }
}

extern "C" void kernel_launch(void* const* d_in, const int* in_sizes, int n_in,
                              void* d_out, int out_size, void* d_ws, size_t ws_size,
                              hipStream_t stream) {
    const float* x    = (const float*)d_in[0];
    const float* Wih0 = (const float*)d_in[1];
    const float* Whh0 = (const float*)d_in[2];
    const float* bih0 = (const float*)d_in[3];
    const float* bhh0 = (const float*)d_in[4];
    const float* Wih1 = (const float*)d_in[5];
    const float* Whh1 = (const float*)d_in[6];
    const float* bih1 = (const float*)d_in[7];
    const float* bhh1 = (const float*)d_in[8];
    const float* Wfc  = (const float*)d_in[9];
    const float* bfc  = (const float*)d_in[10];
    float* out = (float*)d_out;

    // Full batch: 4096 rows / 2 rows per 2-wave block = 2048 blocks
    // = 4096 waves (16/CU at 4 waves/SIMD if VGPR<=128, else 12/CU).
    rnn2_split<<<2048, 128, 0, stream>>>(x, Wih0, Whh0, bih0, bhh0,
                                         Wih1, Whh1, bih1, bhh1, Wfc, bfc, out);
}

// Round 11
// 641.339 us; speedup vs baseline: 2.0484x; 1.0791x over previous
//
#include <hip/hip_runtime.h>

#define TT   256
#define INH  28
#define HH   64
#define OUTN 10
#define ROWS 4    // batch rows per block

// tanh(x) = 1 - 2/(e^{2x}+1), clamped so e^{2x} can't overflow.
__device__ __forceinline__ float fast_tanh(float x) {
    float cx = fminf(fmaxf(x, -15.0f), 15.0f);
    float e2 = __expf(2.0f * cx);
    return 1.0f - 2.0f * __builtin_amdgcn_rcpf(e2 + 1.0f);
}

// 4-wave, 4-stage software pipeline; ONE matrix (<=64 weight floats/lane)
// per wave so the allocator can fit honestly under the 128-VGPR cap of
// waves_per_eu(4,4). (R2/R9 lesson: >~80 live floats => AGPR/scratch
// shuttles, 1.5-2.2x instr bloat; R9 VGPR=84 + WRITE_SIZE=3.3MB proved it.)
//   role0: xp(t)   = Wih0·x(t) + bias0          (28 w)
//   role1: h0(t-1) = tanh(xp(t-1) + Whh0·h0(t-2))   (64 w)
//   role2: u(t-2)  = Wih1·h0(t-2)               (64 w)
//   role3: h1(t-3) = tanh(u(t-3) + bias1 + Whh1·h1(t-4)); FC epilogue (64 w)
// Handoffs via parity ring buffers (slot = step & 1); every cross-wave
// RAW/WAR pair is opposite-parity within an iteration or separated by the
// single end-of-iteration barrier (scheme proven in R8/R9). Pointwise
// values (xp, u) pass as 1 ds_*_b32 per row; h broadcasts are uniform
// ds_read_b128 (conflict-free). Roles rotate with blockIdx so each SIMD
// hosts a mix of heavy/light roles. 1024 blocks x 4 waves = 4096 waves =
// exactly 4/SIMD machine-wide, single pass.
__global__ __launch_bounds__(256)
__attribute__((amdgpu_waves_per_eu(4, 4)))
void rnn2_pipe4(const float* __restrict__ x,
                const float* __restrict__ Wih0, const float* __restrict__ Whh0,
                const float* __restrict__ bih0, const float* __restrict__ bhh0,
                const float* __restrict__ Wih1, const float* __restrict__ Whh1,
                const float* __restrict__ bih1, const float* __restrict__ bhh1,
                const float* __restrict__ Wfc,  const float* __restrict__ bfc,
                float* __restrict__ out)
{
    __shared__ __align__(16) float xl [2][ROWS][32];  // x staging (28 used, pad 32)
    __shared__ __align__(16) float xpR[2][ROWS][HH];  // xp ring  (pointwise)
    __shared__ __align__(16) float h0R[2][ROWS][HH];  // h0 ring  (broadcast)
    __shared__ __align__(16) float uR [2][ROWS][HH];  // u  ring  (pointwise)
    __shared__ __align__(16) float h1R[2][ROWS][HH];  // h1 state (role3-private)

    const int tid  = threadIdx.x;
    const int lane = tid & 63;
    const int wv   = tid >> 6;
    const int role = (wv + (int)blockIdx.x) & 3;      // rotate roles across SIMDs
    const int b0   = (int)blockIdx.x * ROWS;

    // ---- per-role weight row in VGPRs (<=64 floats, static indices only) ----
    float w[HH];
    if (role == 0) {
#pragma unroll
        for (int k = 0; k < INH; ++k) w[k] = Wih0[lane * INH + k];
#pragma unroll
        for (int k = INH; k < HH; ++k) w[k] = 0.0f;
    } else {
        const float* wsrc = (role == 1) ? Whh0 : (role == 2) ? Wih1 : Whh1;
#pragma unroll
        for (int k = 0; k < HH; ++k) w[k] = wsrc[lane * HH + k];
    }
    float bias = 0.0f;
    if (role == 0) bias = bih0[lane] + bhh0[lane];
    if (role == 3) bias = bih1[lane] + bhh1[lane];

    // ---- x staging map: element e in [0,112) -> (row e/28, col e%28);
    //      lane covers e=lane and e=lane+64 (second only if lane<48) ----
    const int row0 = lane / INH, col0 = lane - row0 * INH;
    const int e1 = lane + 64;
    const int row1g = e1 / INH, col1 = e1 - row1g * INH;
    const int row1 = (row1g < ROWS) ? row1g : (ROWS - 1);   // clamp (unused lanes)
    const float* px0 = x + (size_t)(b0 + row0) * (TT * INH) + col0;
    const float* px1 = x + (size_t)(b0 + row1) * (TT * INH) + col1;

    // ---- init: zero h0/h1 rings; stage x(0) ----
    for (int i = tid; i < 2 * ROWS * HH; i += 256) {
        ((float*)h0R)[i] = 0.0f;
        ((float*)h1R)[i] = 0.0f;
    }
    if (role == 0) {
        xl[0][row0][col0] = px0[0];
        if (lane < 48) xl[0][row1][col1] = px1[0];
    }
    __syncthreads();

#pragma unroll 1
    for (int t = 0; t <= TT + 2; ++t) {
        if (role == 0) {
            if (t < TT) {
                const int tn = (t + 1 < TT) ? (t + 1) : (TT - 1);
                const float xv0 = px0[(size_t)tn * INH];
                float xv1 = 0.0f;
                if (lane < 48) xv1 = px1[(size_t)tn * INH];

                float xpv[ROWS];
#pragma unroll
                for (int r = 0; r < ROWS; ++r) {
                    const float4* xq = (const float4*)xl[t & 1][r];
                    float a0 = bias, a1 = 0.0f;
#pragma unroll
                    for (int i = 0; i < 7; ++i) {
                        float4 v = xq[i];
                        a0 = fmaf(v.x, w[4*i+0], a0);
                        a1 = fmaf(v.y, w[4*i+1], a1);
                        a0 = fmaf(v.z, w[4*i+2], a0);
                        a1 = fmaf(v.w, w[4*i+3], a1);
                    }
                    xpv[r] = a0 + a1;
                }
#pragma unroll
                for (int r = 0; r < ROWS; ++r) xpR[t & 1][r][lane] = xpv[r];
                xl[(t + 1) & 1][row0][col0] = xv0;
                if (lane < 48) xl[(t + 1) & 1][row1][col1] = xv1;
            }
        } else if (role == 1) {
            if (t >= 1 && t <= TT) {
                const int sw = (t - 1) & 1;   // xp(t-1) slot == h0 publish slot
                const int sr = t & 1;         // h0(t-2) slot
                float hv[ROWS];
#pragma unroll
                for (int r = 0; r < ROWS; ++r) {
                    float a0 = xpR[sw][r][lane], a1 = 0.0f;
                    const float4* hq = (const float4*)h0R[sr][r];
#pragma unroll
                    for (int kk = 0; kk < 16; ++kk) {
                        float4 v = hq[kk];
                        a0 = fmaf(v.x, w[4*kk+0], a0);
                        a1 = fmaf(v.y, w[4*kk+1], a1);
                        a0 = fmaf(v.z, w[4*kk+2], a0);
                        a1 = fmaf(v.w, w[4*kk+3], a1);
                    }
                    hv[r] = fast_tanh(a0 + a1);
                }
#pragma unroll
                for (int r = 0; r < ROWS; ++r) h0R[sw][r][lane] = hv[r];
            }
        } else if (role == 2) {
            if (t >= 2 && t <= TT + 1) {
                const int sr = t & 1;         // h0(t-2) slot == u publish slot
                float uv[ROWS];
#pragma unroll
                for (int r = 0; r < ROWS; ++r) {
                    float a0 = 0.0f, a1 = 0.0f;
                    const float4* hq = (const float4*)h0R[sr][r];
#pragma unroll
                    for (int kk = 0; kk < 16; ++kk) {
                        float4 v = hq[kk];
                        a0 = fmaf(v.x, w[4*kk+0], a0);
                        a1 = fmaf(v.y, w[4*kk+1], a1);
                        a0 = fmaf(v.z, w[4*kk+2], a0);
                        a1 = fmaf(v.w, w[4*kk+3], a1);
                    }
                    uv[r] = a0 + a1;
                }
#pragma unroll
                for (int r = 0; r < ROWS; ++r) uR[sr][r][lane] = uv[r];
            }
        } else {
            if (t >= 3) {
                const int su = (t - 1) & 1;   // u(t-3) slot == h1 publish slot
                const int sr = t & 1;         // h1(t-4) slot
                float hv[ROWS];
#pragma unroll
                for (int r = 0; r < ROWS; ++r) {
                    float a0 = uR[su][r][lane] + bias, a1 = 0.0f;
                    const float4* hq = (const float4*)h1R[sr][r];
#pragma unroll
                    for (int kk = 0; kk < 16; ++kk) {
                        float4 v = hq[kk];
                        a0 = fmaf(v.x, w[4*kk+0], a0);
                        a1 = fmaf(v.y, w[4*kk+1], a1);
                        a0 = fmaf(v.z, w[4*kk+2], a0);
                        a1 = fmaf(v.w, w[4*kk+3], a1);
                    }
                    hv[r] = fast_tanh(a0 + a1);
                }
#pragma unroll
                for (int r = 0; r < ROWS; ++r) h1R[su][r][lane] = hv[r];
            }
        }
        __syncthreads();
    }

    // ---- FC epilogue on h1(TT-1) (slot (TT-1)&1), by role-3 wave ----
    if (role == 3 && lane < OUTN) {
        const float4* wrow = (const float4*)(Wfc + lane * HH);
        const float bf = bfc[lane];
#pragma unroll
        for (int r = 0; r < ROWS; ++r) {
            const float4* hq = (const float4*)h1R[(TT - 1) & 1][r];
            float a0 = bf, a1 = 0.0f;
#pragma unroll
            for (int kk = 0; kk < 16; ++kk) {
                float4 wv = wrow[kk];
                float4 hvv = hq[kk];
                a0 = fmaf(hvv.x, wv.x, a0);
                a1 = fmaf(hvv.y, wv.y, a1);
                a0 = fmaf(hvv.z, wv.z, a0);
                a1 = fmaf(hvv.w, wv.w, a1);
            }
            out[(size_t)(b0 + r) * OUTN + lane] = a0 + a1;
        }
    }
}

extern "C" void kernel_launch(void* const* d_in, const int* in_sizes, int n_in,
                              void* d_out, int out_size, void* d_ws, size_t ws_size,
                              hipStream_t stream) {
    const float* x    = (const float*)d_in[0];
    const float* Wih0 = (const float*)d_in[1];
    const float* Whh0 = (const float*)d_in[2];
    const float* bih0 = (const float*)d_in[3];
    const float* bhh0 = (const float*)d_in[4];
    const float* Wih1 = (const float*)d_in[5];
    const float* Whh1 = (const float*)d_in[6];
    const float* bih1 = (const float*)d_in[7];
    const float* bhh1 = (const float*)d_in[8];
    const float* Wfc  = (const float*)d_in[9];
    const float* bfc  = (const float*)d_in[10];
    float* out = (float*)d_out;

    // 4096 rows / 4 rows per block = 1024 blocks x 4 waves = 4096 waves
    // = exactly 4 waves/SIMD machine-wide, single pass, all resident.
    rnn2_pipe4<<<1024, 256, 0, stream>>>(x, Wih0, Whh0, bih0, bhh0,
                                         Wih1, Whh1, bih1, bhh1, Wfc, bfc, out);
}